// Round 1
// baseline (126.329 us; speedup 1.0000x reference)
//
#include <hip/hip_runtime.h>

typedef float v2f __attribute__((ext_vector_type(2)));
typedef float v4f __attribute__((ext_vector_type(4)));

#define NF     10            // NUM_FEAT
#define NF2    5             // NF/2 (float2 pairs)
#define NPAD   16            // padded row length for q/k/v in workspace
#define CIN    64
#define N_TOT  8192          // T*H*W
#define HW     1024          // H*W
#define MTILE  128           // m-rows staged in LDS per iteration
#define MSPLIT 16            // parallel splits over m (partial sums + atomicAdd)
#define MCHUNK (N_TOT / MSPLIT)

// ---------------------------------------------------------------------------
// Stage 1: q/k/v projections. grid = (N/256, 3); blockIdx.y selects which
// projection (0:q from in1/w1, 1:k from in2/w2, 2:v from in1/w3).
// Output rows padded to NPAD floats (pad zeroed).
// ---------------------------------------------------------------------------
__global__ __launch_bounds__(256) void qkv_kernel(
    const float* __restrict__ in1, const float* __restrict__ in2,
    const float* __restrict__ w1, const float* __restrict__ b1,
    const float* __restrict__ w2, const float* __restrict__ b2,
    const float* __restrict__ w3, const float* __restrict__ b3,
    float* __restrict__ qd, float* __restrict__ kd, float* __restrict__ vd)
{
    const int which = blockIdx.y;                       // wave-uniform
    const float* x = (which == 1) ? in2 : in1;
    const float* w = (which == 0) ? w1 : ((which == 1) ? w2 : w3);
    const float* b = (which == 0) ? b1 : ((which == 1) ? b2 : b3);
    float* dst     = (which == 0) ? qd : ((which == 1) ? kd : vd);

    const int n  = blockIdx.x * 256 + threadIdx.x;      // 0..8191
    const int t  = n >> 10;                             // n / (H*W)
    const int hw = n & 1023;
    // input[t][c][hw] : ((t*CIN + c)*HW + hw)
    const float* p = x + (size_t)t * (CIN * HW) + hw;

    float acc[NF];
#pragma unroll
    for (int f = 0; f < NF; ++f) acc[f] = b[f];         // bias folded in

#pragma unroll 8
    for (int c = 0; c < CIN; ++c) {
        float a = p[c * HW];                            // coalesced across threads
#pragma unroll
        for (int f = 0; f < NF; ++f)
            acc[f] = fmaf(w[f * CIN + c], a, acc[f]);   // w loads wave-uniform -> s_load
    }

    float* o = dst + (size_t)n * NPAD;
#pragma unroll
    for (int f = 0; f < NF; ++f) o[f] = acc[f];
#pragma unroll
    for (int f = NF; f < NPAD; ++f) o[f] = 0.f;
}

// ---------------------------------------------------------------------------
// Stage 2: out[n,f] = sum_m relu(q[n]·k[m]) * v[m,f], flash-style (no N×N
// materialization). One thread per n; LDS-staged k/v m-tiles; m split over
// blockIdx.y with fp32 atomicAdd into the (zeroed) output.
// Output layout: [T, F, H, W] -> index t*F*HW + f*HW + hw.
// ---------------------------------------------------------------------------
__global__ __launch_bounds__(256) void attn_kernel(
    const float* __restrict__ qd, const float* __restrict__ kd,
    const float* __restrict__ vd, float* __restrict__ out)
{
    __shared__ v2f ks[MTILE][NPAD / 2];   // 128 x 8 float2 = 8 KB
    __shared__ v2f vs[MTILE][NPAD / 2];   // 8 KB

    const int tid = threadIdx.x;
    const int n   = blockIdx.x * 256 + tid;
    const int m0  = blockIdx.y * MCHUNK;

    v2f q2[NF2];
#pragma unroll
    for (int j = 0; j < NF2; ++j)
        q2[j] = *(const v2f*)(qd + (size_t)n * NPAD + 2 * j);

    v2f acc[NF2];
#pragma unroll
    for (int j = 0; j < NF2; ++j) acc[j] = (v2f)(0.f);

    for (int mt = 0; mt < MCHUNK; mt += MTILE) {
        const float* kb = kd + (size_t)(m0 + mt) * NPAD;
        const float* vb = vd + (size_t)(m0 + mt) * NPAD;
        // MTILE*NPAD = 2048 floats = 512 float4; 256 threads -> 2 each per array
#pragma unroll
        for (int i = 0; i < 2; ++i) {
            int idx = tid + i * 256;
            ((v4f*)ks)[idx] = ((const v4f*)kb)[idx];
            ((v4f*)vs)[idx] = ((const v4f*)vb)[idx];
        }
        __syncthreads();

#pragma unroll 2
        for (int m = 0; m < MTILE; ++m) {
            // dot(q[n], k[m]) over 10 feats as 5 packed-f32 fmas (broadcast LDS reads)
            v2f d = q2[0] * ks[m][0];
            d = __builtin_elementwise_fma(q2[1], ks[m][1], d);
            d = __builtin_elementwise_fma(q2[2], ks[m][2], d);
            d = __builtin_elementwise_fma(q2[3], ks[m][3], d);
            d = __builtin_elementwise_fma(q2[4], ks[m][4], d);
            float s = fmaxf(d.x + d.y, 0.f);            // relu
            v2f s2 = (v2f)(s);
#pragma unroll
            for (int j = 0; j < NF2; ++j)
                acc[j] = __builtin_elementwise_fma(s2, vs[m][j], acc[j]);
        }
        __syncthreads();
    }

    const int t  = n >> 10;
    const int hw = n & 1023;
    float* op = out + (size_t)t * (NF * HW) + hw;
#pragma unroll
    for (int j = 0; j < NF2; ++j) {
        atomicAdd(op + (2 * j) * HW,     acc[j].x);
        atomicAdd(op + (2 * j + 1) * HW, acc[j].y);
    }
}

extern "C" void kernel_launch(void* const* d_in, const int* in_sizes, int n_in,
                              void* d_out, int out_size, void* d_ws, size_t ws_size,
                              hipStream_t stream)
{
    const float* in1 = (const float*)d_in[0];
    const float* in2 = (const float*)d_in[1];
    const float* w1  = (const float*)d_in[2];
    const float* b1  = (const float*)d_in[3];
    const float* w2  = (const float*)d_in[4];
    const float* b2  = (const float*)d_in[5];
    const float* w3  = (const float*)d_in[6];
    const float* b3  = (const float*)d_in[7];

    // workspace: q | k | v, each N_TOT x NPAD fp32  (total 1.57 MB)
    float* q = (float*)d_ws;
    float* k = q + (size_t)N_TOT * NPAD;
    float* v = k + (size_t)N_TOT * NPAD;
    float* out = (float*)d_out;

    // output is accumulated via atomics -> must start at zero every call
    hipMemsetAsync(d_out, 0, (size_t)out_size * sizeof(float), stream);

    qkv_kernel<<<dim3(N_TOT / 256, 3), 256, 0, stream>>>(
        in1, in2, w1, b1, w2, b2, w3, b3, q, k, v);

    attn_kernel<<<dim3(N_TOT / 256, MSPLIT), 256, 0, stream>>>(q, k, v, out);
}

// Round 2
// 115.023 us; speedup vs baseline: 1.0983x; 1.0983x over previous
//
#include <hip/hip_runtime.h>

typedef short  s4  __attribute__((ext_vector_type(4)));   // 4 bf16 in 2 VGPRs
typedef float  f4  __attribute__((ext_vector_type(4)));
typedef unsigned int u2v __attribute__((ext_vector_type(2)));
typedef unsigned int uint32;
typedef unsigned short ushort16;

#define NF     10
#define CIN    64
#define NTOT   8192          // T*H*W
#define HW     1024
#define FPAD   16            // feature dim padded for MFMA K
#define MSPLIT 8             // m-splits (partials via atomicAdd)
#define MCHUNK (NTOT / MSPLIT)   // 1024 m per wave

// ---- v_mfma_f32_16x16x16_bf16: D[i][j], i=4*(lane/16)+reg (M), j=lane%16 (N)
//      A[i][k]: i=lane%16, k=4*(lane/16)+jj ; B[k][j]: j=lane%16, k=4*(lane/16)+jj
#if defined(__has_builtin) && __has_builtin(__builtin_amdgcn_mfma_f32_16x16x16bf16_1k)
#define MFMA16(a, b, c) __builtin_amdgcn_mfma_f32_16x16x16bf16_1k((a), (b), (c), 0, 0, 0)
#else
static __device__ inline f4 mfma16_asm(s4 a, s4 b, f4 c) {
    f4 d;
    asm volatile("s_nop 1\n\t"
                 "v_mfma_f32_16x16x16_bf16 %0, %1, %2, %3\n\t"
                 "s_nop 7\n\ts_nop 7"
                 : "=v"(d) : "v"(a), "v"(b), "v"(c));
    return d;
}
#define MFMA16(a, b, c) mfma16_asm((a), (b), (c))
#endif

static __device__ inline ushort16 f32_to_bf16_rne(float x) {
    uint32 u = __builtin_bit_cast(uint32, x);
    u = (u + 0x7fffu + ((u >> 16) & 1u)) >> 16;
    return (ushort16)u;
}

// ---------------------------------------------------------------------------
// Stage 1: q/k/v projections -> bf16 workspace.
//   qb[n][16] bf16 (pad zeroed), kb[n][16] bf16 (pad zeroed), vT[f][n] bf16.
// grid = (NTOT/256, 3): y=0 -> q(in1,w1), y=1 -> k(in2,w2), y=2 -> v(in1,w3).
// ---------------------------------------------------------------------------
__global__ __launch_bounds__(256) void qkv_bf16_kernel(
    const float* __restrict__ in1, const float* __restrict__ in2,
    const float* __restrict__ w1, const float* __restrict__ b1,
    const float* __restrict__ w2, const float* __restrict__ b2,
    const float* __restrict__ w3, const float* __restrict__ b3,
    ushort16* __restrict__ qb, ushort16* __restrict__ kb,
    ushort16* __restrict__ vT)
{
    const int which = blockIdx.y;   // wave-uniform
    const float* x = (which == 1) ? in2 : in1;
    const float* w = (which == 0) ? w1 : ((which == 1) ? w2 : w3);
    const float* b = (which == 0) ? b1 : ((which == 1) ? b2 : b3);

    const int n  = blockIdx.x * 256 + threadIdx.x;
    const int t  = n >> 10;
    const int hw = n & 1023;
    const float* p = x + (size_t)t * (CIN * HW) + hw;   // input[t][c][hw]

    float acc[NF];
#pragma unroll
    for (int f = 0; f < NF; ++f) acc[f] = b[f];
#pragma unroll 8
    for (int c = 0; c < CIN; ++c) {
        float a = p[c * HW];                      // coalesced; w is s_load
#pragma unroll
        for (int f = 0; f < NF; ++f) acc[f] = fmaf(w[f * CIN + c], a, acc[f]);
    }

    if (which == 2) {
        // v transposed: vT[f][n]  (rows 10..15 never influence written output)
#pragma unroll
        for (int f = 0; f < NF; ++f) vT[(size_t)f * NTOT + n] = f32_to_bf16_rne(acc[f]);
    } else {
        ushort16 row[FPAD];
#pragma unroll
        for (int f = 0; f < NF; ++f) row[f] = f32_to_bf16_rne(acc[f]);
#pragma unroll
        for (int f = NF; f < FPAD; ++f) row[f] = 0;    // K-dim pad MUST be zero
        ushort16* dst = ((which == 0) ? qb : kb) + (size_t)n * FPAD;
        ((uint4*)dst)[0] = ((const uint4*)row)[0];     // 32B/thread, coalesced
        ((uint4*)dst)[1] = ((const uint4*)row)[1];
    }
}

// ---------------------------------------------------------------------------
// Stage 2: flash-style MFMA attention, one wave per 16-n tile x m-chunk.
//   S'[m][n] = mfma(Kfrag, Qfrag)  -> relu -> trunc bf16 (D layout == B layout)
//   out'[f][n] += mfma(VTfrag, P')
// grid = (NTOT/64, MSPLIT), block 256 (4 waves). No LDS at all.
// ---------------------------------------------------------------------------
__global__ __launch_bounds__(256) void attn_mfma_kernel(
    const ushort16* __restrict__ qb, const ushort16* __restrict__ kb,
    const ushort16* __restrict__ vT, float* __restrict__ out)
{
    const int lane = threadIdx.x & 63;
    const int wid  = threadIdx.x >> 6;
    const int row  = lane & 15;          // n-offset / m-row / f-row per operand
    const int quad = lane >> 4;          // k-quarter
    const int n0   = blockIdx.x * 64 + wid * 16;
    const int m0   = blockIdx.y * MCHUNK;

    // Q-frag (B operand): q[n0+row][4*quad + 0..3], loop-invariant
    const s4 qf = *(const s4*)(qb + (size_t)(n0 + row) * FPAD + 4 * quad);

    // K-frag stream (A op of mfma1): k[m0+step*16+row][4*quad+0..3]
    const s4* kp = (const s4*)(kb + (size_t)(m0 + row) * FPAD + 4 * quad);
    // V-frag stream (A op of mfma2): vT[row][m0+step*16+4*quad+0..3]
    const s4* vp = (const s4*)(vT + (size_t)row * NTOT + m0 + 4 * quad);

    f4 acc  = {0.f, 0.f, 0.f, 0.f};
    const f4 zero = {0.f, 0.f, 0.f, 0.f};

#pragma unroll 8
    for (int s = 0; s < MCHUNK / 16; ++s) {
        s4 kf = kp[s * 64];              // 16 rows * 32B = 512B per step
        s4 vf = vp[s * 4];               // 16 bf16 = 32B per step

        f4 sc = MFMA16(kf, qf, zero);    // S'[m0+16s+4q+r][n0+row]

        // relu + truncate-pack f32->bf16 (2x v_perm); bias ~0.2% << threshold
        float r0 = fmaxf(sc[0], 0.f), r1 = fmaxf(sc[1], 0.f);
        float r2 = fmaxf(sc[2], 0.f), r3 = fmaxf(sc[3], 0.f);
        uint32 lo = __builtin_amdgcn_perm(__builtin_bit_cast(uint32, r1),
                                          __builtin_bit_cast(uint32, r0), 0x07060302u);
        uint32 hi = __builtin_amdgcn_perm(__builtin_bit_cast(uint32, r3),
                                          __builtin_bit_cast(uint32, r2), 0x07060302u);
        s4 pb = __builtin_bit_cast(s4, (u2v){lo, hi});   // B-operand ready

        acc = MFMA16(vf, pb, acc);       // out'[f=4q+r][n0+row]
    }

    // Epilogue: out[t][f][h][w]; lane holds f=4*quad+r, n=n0+row
    const int n  = n0 + row;
    const int t  = n >> 10;
    const int hw = n & 1023;
    float* op = out + (size_t)t * (NF * HW) + hw;
    const int fbase = 4 * quad;
#pragma unroll
    for (int r = 0; r < 4; ++r) {
        int f = fbase + r;
        if (f < NF) atomicAdd(op + f * HW, acc[r]);
    }
}

extern "C" void kernel_launch(void* const* d_in, const int* in_sizes, int n_in,
                              void* d_out, int out_size, void* d_ws, size_t ws_size,
                              hipStream_t stream)
{
    const float* in1 = (const float*)d_in[0];
    const float* in2 = (const float*)d_in[1];
    const float* w1  = (const float*)d_in[2];
    const float* b1  = (const float*)d_in[3];
    const float* w2  = (const float*)d_in[4];
    const float* b2  = (const float*)d_in[5];
    const float* w3  = (const float*)d_in[6];
    const float* b3  = (const float*)d_in[7];

    // bf16 workspace: qb | kb | vT, each NTOT*16 elements (256 KB) = 768 KB
    ushort16* qb = (ushort16*)d_ws;
    ushort16* kb = qb + (size_t)NTOT * FPAD;
    ushort16* vT = kb + (size_t)NTOT * FPAD;
    float* out = (float*)d_out;

    hipMemsetAsync(d_out, 0, (size_t)out_size * sizeof(float), stream);

    qkv_bf16_kernel<<<dim3(NTOT / 256, 3), 256, 0, stream>>>(
        in1, in2, w1, b1, w2, b2, w3, b3, qb, kb, vT);

    attn_mfma_kernel<<<dim3(NTOT / 64, MSPLIT), 256, 0, stream>>>(qb, kb, vT, out);
}

// Round 3
// 110.196 us; speedup vs baseline: 1.1464x; 1.0438x over previous
//
#include <hip/hip_runtime.h>

typedef short  s4  __attribute__((ext_vector_type(4)));   // 4 bf16 in 2 VGPRs
typedef float  f4  __attribute__((ext_vector_type(4)));
typedef unsigned int u2v __attribute__((ext_vector_type(2)));
typedef unsigned int uint32;
typedef unsigned short ushort16;

#define NF      10
#define CIN     64
#define NTOT    8192              // T*H*W
#define HW      1024
#define FPAD    16                // feature dim padded for MFMA K
#define MSPLIT  8                 // m-splits (partials -> reduce kernel)
#define MCHUNK  (NTOT / MSPLIT)   // 1024 m per wave
#define PSTRIDE 16                // f-stride of partial buffer

// ---- v_mfma_f32_16x16x16_bf16: D[i][j], i=4*(lane/16)+reg (M), j=lane%16 (N)
//      A[i][k]: i=lane%16, k=4*(lane/16)+jj ; B[k][j]: j=lane%16, k=4*(lane/16)+jj
//      Verified empirically in R2 (passed, absmax 0.25 fp32 / 32 bf16).
#if defined(__has_builtin) && __has_builtin(__builtin_amdgcn_mfma_f32_16x16x16bf16_1k)
#define MFMA16(a, b, c) __builtin_amdgcn_mfma_f32_16x16x16bf16_1k((a), (b), (c), 0, 0, 0)
#else
static __device__ inline f4 mfma16_asm(s4 a, s4 b, f4 c) {
    f4 d;
    asm volatile("s_nop 1\n\t"
                 "v_mfma_f32_16x16x16_bf16 %0, %1, %2, %3\n\t"
                 "s_nop 7\n\ts_nop 7"
                 : "=v"(d) : "v"(a), "v"(b), "v"(c));
    return d;
}
#define MFMA16(a, b, c) mfma16_asm((a), (b), (c))
#endif

static __device__ inline ushort16 f32_to_bf16_rne(float x) {
    uint32 u = __builtin_bit_cast(uint32, x);
    u = (u + 0x7fffu + ((u >> 16) & 1u)) >> 16;
    return (ushort16)u;
}

// ---------------------------------------------------------------------------
// Stage 1: projections -> bf16 workspace.
//   y==0: q AND v from in1 (shares the 8 MB input read); y==1: k from in2.
//   qb[n][16], kb[n][16] row-major bf16 (pad zeroed).
//   vtile: V pre-swizzled into MFMA A-fragment order so stage 2's load is
//   fully coalesced: element (f, m) at  (m/16)*256 + ((m%16/4)*16 + f)*4 + m%4.
// grid (NTOT/64, 2), block 64 -> 256 blocks = 1 wave/CU.
// ---------------------------------------------------------------------------
__global__ __launch_bounds__(64) void qkv_kernel(
    const float* __restrict__ in1, const float* __restrict__ in2,
    const float* __restrict__ w1, const float* __restrict__ b1,
    const float* __restrict__ w2, const float* __restrict__ b2,
    const float* __restrict__ w3, const float* __restrict__ b3,
    ushort16* __restrict__ qb, ushort16* __restrict__ kb,
    ushort16* __restrict__ vtile)
{
    const int n  = blockIdx.x * 64 + threadIdx.x;
    const int t  = n >> 10;
    const int hw = n & 1023;

    if (blockIdx.y == 0) {
        const float* p = in1 + (size_t)t * (CIN * HW) + hw;
        float aq[NF], av[NF];
#pragma unroll
        for (int f = 0; f < NF; ++f) { aq[f] = b1[f]; av[f] = b3[f]; }
#pragma unroll 8
        for (int c = 0; c < CIN; ++c) {
            float a = p[c * HW];                       // coalesced; w via s_load
#pragma unroll
            for (int f = 0; f < NF; ++f) {
                aq[f] = fmaf(w1[f * CIN + c], a, aq[f]);
                av[f] = fmaf(w3[f * CIN + c], a, av[f]);
            }
        }
        // q row (32B vector store)
        ushort16 row[FPAD];
#pragma unroll
        for (int f = 0; f < NF; ++f) row[f] = f32_to_bf16_rne(aq[f]);
#pragma unroll
        for (int f = NF; f < FPAD; ++f) row[f] = 0;    // K-pad MUST be zero
        ushort16* dq = qb + (size_t)n * FPAD;
        ((uint4*)dq)[0] = ((const uint4*)row)[0];
        ((uint4*)dq)[1] = ((const uint4*)row)[1];
        // v in fragment order: tile = n>>4, mi = n&15 -> (quad=mi>>2, jj=mi&3)
        const int tile = n >> 4, mi = n & 15;
        const int quad = mi >> 2, jj = mi & 3;
        ushort16* vb = vtile + (size_t)tile * 256 + jj;
#pragma unroll
        for (int f = 0; f < FPAD; ++f)
            vb[(quad * 16 + f) * 4] = (f < NF) ? f32_to_bf16_rne(av[f]) : (ushort16)0;
    } else {
        const float* p = in2 + (size_t)t * (CIN * HW) + hw;
        float ak[NF];
#pragma unroll
        for (int f = 0; f < NF; ++f) ak[f] = b2[f];
#pragma unroll 8
        for (int c = 0; c < CIN; ++c) {
            float a = p[c * HW];
#pragma unroll
            for (int f = 0; f < NF; ++f) ak[f] = fmaf(w2[f * CIN + c], a, ak[f]);
        }
        ushort16 row[FPAD];
#pragma unroll
        for (int f = 0; f < NF; ++f) row[f] = f32_to_bf16_rne(ak[f]);
#pragma unroll
        for (int f = NF; f < FPAD; ++f) row[f] = 0;
        ushort16* dk = kb + (size_t)n * FPAD;
        ((uint4*)dk)[0] = ((const uint4*)row)[0];
        ((uint4*)dk)[1] = ((const uint4*)row)[1];
    }
}

// ---------------------------------------------------------------------------
// Stage 2: MFMA attention, one wave per 16-n tile x m-chunk. No LDS, no
// atomics. Both K and V fragment streams are contiguous 512 B/step.
//   S'[m][n] = mfma(Kfrag, Qfrag) -> relu -> bf16   (D layout == B layout)
//   out'[f][n] += mfma(Vfrag, P')
// Partials to pws[y][f][n]; grid (NTOT/64, MSPLIT), block 256.
// ---------------------------------------------------------------------------
__global__ __launch_bounds__(256) void attn_mfma_kernel(
    const ushort16* __restrict__ qb, const ushort16* __restrict__ kb,
    const ushort16* __restrict__ vtile, float* __restrict__ pws)
{
    const int lane = threadIdx.x & 63;
    const int wid  = threadIdx.x >> 6;
    const int row  = lane & 15;
    const int quad = lane >> 4;
    const int n0   = blockIdx.x * 64 + wid * 16;
    const int m0   = blockIdx.y * MCHUNK;

    // Q-frag (B op), loop-invariant
    const s4 qf = *(const s4*)(qb + (size_t)(n0 + row) * FPAD + 4 * quad);
    // K-frag stream (A op of mfma1): 512 B contiguous per step
    const s4* kp = (const s4*)(kb + (size_t)(m0 + row) * FPAD + 4 * quad);
    // V-frag stream (A op of mfma2): pre-swizzled, 512 B contiguous per step
    const s4* vp = (const s4*)(vtile + (size_t)(m0 >> 4) * 256) + lane;

    f4 acc = {0.f, 0.f, 0.f, 0.f};
    const f4 zero = {0.f, 0.f, 0.f, 0.f};

#pragma unroll 8
    for (int s = 0; s < MCHUNK / 16; ++s) {
        s4 kf = kp[s * 64];
        s4 vf = vp[s * 64];

        f4 sc = MFMA16(kf, qf, zero);    // S'[m0+16s+4q+r][n0+row]

        float r0 = fmaxf(sc[0], 0.f), r1 = fmaxf(sc[1], 0.f);
        float r2 = fmaxf(sc[2], 0.f), r3 = fmaxf(sc[3], 0.f);
        uint32 lo = __builtin_amdgcn_perm(__builtin_bit_cast(uint32, r1),
                                          __builtin_bit_cast(uint32, r0), 0x07060302u);
        uint32 hi = __builtin_amdgcn_perm(__builtin_bit_cast(uint32, r3),
                                          __builtin_bit_cast(uint32, r2), 0x07060302u);
        s4 pb = __builtin_bit_cast(s4, (u2v){lo, hi});   // B-operand ready

        acc = MFMA16(vf, pb, acc);       // out'[f=4q+r][n0+row]
    }

    const int n = n0 + row;
    const int fbase = 4 * quad;
#pragma unroll
    for (int r = 0; r < 4; ++r) {
        int f = fbase + r;
        if (f < NF)
            pws[((size_t)blockIdx.y * PSTRIDE + f) * NTOT + n] = acc[r];
    }
}

// ---------------------------------------------------------------------------
// Stage 3: sum MSPLIT partials, write out[t][f][h][w]. grid 320 x 256.
// ---------------------------------------------------------------------------
__global__ __launch_bounds__(256) void reduce_kernel(
    const float* __restrict__ pws, float* __restrict__ out)
{
    const int gid = blockIdx.x * 256 + threadIdx.x;    // 0 .. NF*NTOT-1
    const int f = gid >> 13;                           // / NTOT
    const int n = gid & (NTOT - 1);
    float s = 0.f;
#pragma unroll
    for (int y = 0; y < MSPLIT; ++y)
        s += pws[((size_t)y * PSTRIDE + f) * NTOT + n];
    const int t = n >> 10, hw = n & 1023;
    out[(size_t)t * (NF * HW) + f * HW + hw] = s;
}

extern "C" void kernel_launch(void* const* d_in, const int* in_sizes, int n_in,
                              void* d_out, int out_size, void* d_ws, size_t ws_size,
                              hipStream_t stream)
{
    const float* in1 = (const float*)d_in[0];
    const float* in2 = (const float*)d_in[1];
    const float* w1  = (const float*)d_in[2];
    const float* b1  = (const float*)d_in[3];
    const float* w2  = (const float*)d_in[4];
    const float* b2  = (const float*)d_in[5];
    const float* w3  = (const float*)d_in[6];
    const float* b3  = (const float*)d_in[7];

    // ws layout: qb | kb | vtile (256 KB each, bf16) | pws (4 MB fp32)
    ushort16* qb    = (ushort16*)d_ws;
    ushort16* kb    = qb + (size_t)NTOT * FPAD;
    ushort16* vtile = kb + (size_t)NTOT * FPAD;
    float*    pws   = (float*)(vtile + (size_t)NTOT * FPAD);
    float*    out   = (float*)d_out;

    qkv_kernel<<<dim3(NTOT / 64, 2), 64, 0, stream>>>(
        in1, in2, w1, b1, w2, b2, w3, b3, qb, kb, vtile);

    attn_mfma_kernel<<<dim3(NTOT / 64, MSPLIT), 256, 0, stream>>>(qb, kb, vtile, pws);

    reduce_kernel<<<dim3(NF * NTOT / 256), 256, 0, stream>>>(pws, out);
}

// Round 4
// 106.262 us; speedup vs baseline: 1.1888x; 1.0370x over previous
//
#include <hip/hip_runtime.h>

typedef short  s4  __attribute__((ext_vector_type(4)));   // 4 bf16 in 2 VGPRs
typedef float  f4  __attribute__((ext_vector_type(4)));
typedef unsigned int u2v __attribute__((ext_vector_type(2)));
typedef unsigned int uint32;
typedef unsigned short ushort16;

#define NF      10
#define CIN     64
#define NTOT    8192              // T*H*W
#define HW      1024
#define FPAD    16                // feature dim padded for MFMA K
#define MSPLIT  16                // m-splits (partials -> reduce kernel)
#define MCHUNK  (NTOT / MSPLIT)   // 512 m per block
#define PSTRIDE 16                // f-stride of partial buffer

// ---- v_mfma_f32_16x16x16_bf16: D[i][j], i=4*(lane/16)+reg (M), j=lane%16 (N)
//      A[i][k]: i=lane%16, k=4*(lane/16)+jj ; B[k][j]: j=lane%16, k=4*(lane/16)+jj
//      D layout == B layout -> relu'd scores feed PV mfma with zero shuffles.
//      Verified empirically R2/R3 (passed, absmax 32 bf16-level).
#if defined(__has_builtin) && __has_builtin(__builtin_amdgcn_mfma_f32_16x16x16bf16_1k)
#define MFMA16(a, b, c) __builtin_amdgcn_mfma_f32_16x16x16bf16_1k((a), (b), (c), 0, 0, 0)
#else
static __device__ inline f4 mfma16_asm(s4 a, s4 b, f4 c) {
    f4 d;
    asm volatile("s_nop 1\n\t"
                 "v_mfma_f32_16x16x16_bf16 %0, %1, %2, %3\n\t"
                 "s_nop 7\n\ts_nop 7"
                 : "=v"(d) : "v"(a), "v"(b), "v"(c));
    return d;
}
#define MFMA16(a, b, c) mfma16_asm((a), (b), (c))
#endif

static __device__ inline ushort16 f32_to_bf16_rne(float x) {
    uint32 u = __builtin_bit_cast(uint32, x);
    u = (u + 0x7fffu + ((u >> 16) & 1u)) >> 16;
    return (ushort16)u;
}

// ---------------------------------------------------------------------------
// Stage 1: projections -> bf16 workspace.
//   y==0: q AND v from in1; y==1: k from in2. All 64 c-values preloaded into
//   registers (64 loads in flight -> covers HBM latency at 1 wave/CU).
//   vtile: V pre-swizzled to MFMA A-frag order via LDS, stored coalesced.
//     element (f, m) at (m/16)*256 + ((m%16/4)*16 + f)*4 + (m%4)   [ushorts]
// grid (NTOT/64, 2), block 64.
// ---------------------------------------------------------------------------
__global__ __launch_bounds__(64) void qkv_kernel(
    const float* __restrict__ in1, const float* __restrict__ in2,
    const float* __restrict__ w1, const float* __restrict__ b1,
    const float* __restrict__ w2, const float* __restrict__ b2,
    const float* __restrict__ w3, const float* __restrict__ b3,
    ushort16* __restrict__ qb, ushort16* __restrict__ kb,
    ushort16* __restrict__ vtile)
{
    __shared__ ushort16 lvs[64][FPAD];                 // v staging, 2 KB

    const int tid = threadIdx.x;
    const int n  = blockIdx.x * 64 + tid;
    const int t  = n >> 10;
    const int hw = n & 1023;

    if (blockIdx.y == 0) {
        const float* p = in1 + (size_t)t * (CIN * HW) + hw;
        float a[CIN];
#pragma unroll
        for (int c = 0; c < CIN; ++c) a[c] = p[c * HW];   // 64 loads in flight

        float aq[NF], av[NF];
#pragma unroll
        for (int f = 0; f < NF; ++f) { aq[f] = b1[f]; av[f] = b3[f]; }
#pragma unroll
        for (int c = 0; c < CIN; ++c) {
#pragma unroll
            for (int f = 0; f < NF; ++f) {
                aq[f] = fmaf(w1[f * CIN + c], a[c], aq[f]);
                av[f] = fmaf(w3[f * CIN + c], a[c], av[f]);
            }
        }
        // q row (32 B vector store)
        ushort16 row[FPAD];
#pragma unroll
        for (int f = 0; f < NF; ++f) row[f] = f32_to_bf16_rne(aq[f]);
#pragma unroll
        for (int f = NF; f < FPAD; ++f) row[f] = 0;       // K-pad MUST be zero
        ushort16* dq = qb + (size_t)n * FPAD;
        ((uint4*)dq)[0] = ((const uint4*)row)[0];
        ((uint4*)dq)[1] = ((const uint4*)row)[1];

        // v: stage to LDS, then coalesced fragment-order store
#pragma unroll
        for (int f = 0; f < NF; ++f) lvs[tid][f] = f32_to_bf16_rne(av[f]);
#pragma unroll
        for (int f = NF; f < FPAD; ++f) lvs[tid][f] = 0;
        __syncthreads();
        // thread j emits ushorts [j*16, j*16+16) of the block's 1024-ushort region
        const int quad = (tid & 15) >> 2;                 // constant per thread
        const int tloc = tid >> 4;                        // local 16-m tile
        ushort16 obuf[16];
#pragma unroll
        for (int e = 0; e < 16; ++e) {
            int f  = ((tid & 3) * 4 + (e >> 2)) & 15;
            int mi = quad * 4 + (e & 3);
            obuf[e] = lvs[tloc * 16 + mi][f];
        }
        ushort16* dv = vtile + (size_t)blockIdx.x * 1024 + tid * 16;
        ((uint4*)dv)[0] = ((const uint4*)obuf)[0];
        ((uint4*)dv)[1] = ((const uint4*)obuf)[1];
    } else {
        const float* p = in2 + (size_t)t * (CIN * HW) + hw;
        float a[CIN];
#pragma unroll
        for (int c = 0; c < CIN; ++c) a[c] = p[c * HW];

        float ak[NF];
#pragma unroll
        for (int f = 0; f < NF; ++f) ak[f] = b2[f];
#pragma unroll
        for (int c = 0; c < CIN; ++c) {
#pragma unroll
            for (int f = 0; f < NF; ++f) ak[f] = fmaf(w2[f * CIN + c], a[c], ak[f]);
        }
        ushort16 row[FPAD];
#pragma unroll
        for (int f = 0; f < NF; ++f) row[f] = f32_to_bf16_rne(ak[f]);
#pragma unroll
        for (int f = NF; f < FPAD; ++f) row[f] = 0;
        ushort16* dk = kb + (size_t)n * FPAD;
        ((uint4*)dk)[0] = ((const uint4*)row)[0];
        ((uint4*)dk)[1] = ((const uint4*)row)[1];
    }
}

// ---------------------------------------------------------------------------
// Stage 2: MFMA attention. Each wave owns FOUR 16-n tiles (64 n) so one
// kf/vf load pair feeds 8 MFMAs (4x less VMEM than R3). No LDS, no atomics.
//   S'[m][ng] = mfma(Kfrag, Qfrag_g) -> relu -> bf16 (D layout == B layout)
//   out'[f][ng] += mfma(Vfrag, P'_g)
// grid (NTOT/256, MSPLIT) = (32,16) = 512 blocks, block 256 (2 blocks/CU).
// ---------------------------------------------------------------------------
__global__ __launch_bounds__(256) void attn_mfma_kernel(
    const ushort16* __restrict__ qb, const ushort16* __restrict__ kb,
    const ushort16* __restrict__ vtile, float* __restrict__ pws)
{
    const int lane = threadIdx.x & 63;
    const int wid  = threadIdx.x >> 6;
    const int row  = lane & 15;
    const int quad = lane >> 4;
    const int nb   = blockIdx.x * 256 + wid * 64;      // wave's 64-n base
    const int m0   = blockIdx.y * MCHUNK;

    // 4 loop-invariant Q-frags (B operand)
    s4 qf[4];
#pragma unroll
    for (int g = 0; g < 4; ++g)
        qf[g] = *(const s4*)(qb + (size_t)(nb + g * 16 + row) * FPAD + 4 * quad);

    // K / V fragment streams: contiguous 512 B per 16-m step
    const s4* kp = (const s4*)(kb + (size_t)(m0 + row) * FPAD + 4 * quad);
    const s4* vp = (const s4*)(vtile + (size_t)(m0 >> 4) * 256) + lane;

    f4 acc[4];
#pragma unroll
    for (int g = 0; g < 4; ++g) acc[g] = (f4){0.f, 0.f, 0.f, 0.f};
    const f4 zero = {0.f, 0.f, 0.f, 0.f};

#pragma unroll 4
    for (int s = 0; s < MCHUNK / 16; ++s) {
        s4 kf = kp[s * 64];
        s4 vf = vp[s * 64];
#pragma unroll
        for (int g = 0; g < 4; ++g) {
            f4 sc = MFMA16(kf, qf[g], zero);           // S'[m][nb+16g+row]
            float r0 = fmaxf(sc[0], 0.f), r1 = fmaxf(sc[1], 0.f);
            float r2 = fmaxf(sc[2], 0.f), r3 = fmaxf(sc[3], 0.f);
            uint32 lo = __builtin_amdgcn_perm(__builtin_bit_cast(uint32, r1),
                                              __builtin_bit_cast(uint32, r0), 0x07060302u);
            uint32 hi = __builtin_amdgcn_perm(__builtin_bit_cast(uint32, r3),
                                              __builtin_bit_cast(uint32, r2), 0x07060302u);
            s4 pb = __builtin_bit_cast(s4, (u2v){lo, hi});
            acc[g] = MFMA16(vf, pb, acc[g]);           // out'[f=4q+r][nb+16g+row]
        }
    }

    const int fbase = 4 * quad;
#pragma unroll
    for (int g = 0; g < 4; ++g) {
        const int n = nb + g * 16 + row;
#pragma unroll
        for (int r = 0; r < 4; ++r) {
            int f = fbase + r;
            if (f < NF)
                pws[((size_t)blockIdx.y * PSTRIDE + f) * NTOT + n] = acc[g][r];
        }
    }
}

// ---------------------------------------------------------------------------
// Stage 3: sum MSPLIT partials, write out[t][f][h][w]. grid 320 x 256.
// ---------------------------------------------------------------------------
__global__ __launch_bounds__(256) void reduce_kernel(
    const float* __restrict__ pws, float* __restrict__ out)
{
    const int gid = blockIdx.x * 256 + threadIdx.x;    // 0 .. NF*NTOT-1
    const int f = gid >> 13;                           // / NTOT
    const int n = gid & (NTOT - 1);
    float s = 0.f;
#pragma unroll
    for (int y = 0; y < MSPLIT; ++y)
        s += pws[((size_t)y * PSTRIDE + f) * NTOT + n];
    const int t = n >> 10, hw = n & 1023;
    out[(size_t)t * (NF * HW) + f * HW + hw] = s;
}

extern "C" void kernel_launch(void* const* d_in, const int* in_sizes, int n_in,
                              void* d_out, int out_size, void* d_ws, size_t ws_size,
                              hipStream_t stream)
{
    const float* in1 = (const float*)d_in[0];
    const float* in2 = (const float*)d_in[1];
    const float* w1  = (const float*)d_in[2];
    const float* b1  = (const float*)d_in[3];
    const float* w2  = (const float*)d_in[4];
    const float* b2  = (const float*)d_in[5];
    const float* w3  = (const float*)d_in[6];
    const float* b3  = (const float*)d_in[7];

    // ws layout: qb | kb | vtile (256 KB each, bf16) | pws (8 MB fp32)
    ushort16* qb    = (ushort16*)d_ws;
    ushort16* kb    = qb + (size_t)NTOT * FPAD;
    ushort16* vtile = kb + (size_t)NTOT * FPAD;
    float*    pws   = (float*)(vtile + (size_t)NTOT * FPAD);
    float*    out   = (float*)d_out;

    qkv_kernel<<<dim3(NTOT / 64, 2), 64, 0, stream>>>(
        in1, in2, w1, b1, w2, b2, w3, b3, qb, kb, vtile);

    attn_mfma_kernel<<<dim3(NTOT / 256, MSPLIT), 256, 0, stream>>>(qb, kb, vtile, pws);

    reduce_kernel<<<dim3(NF * NTOT / 256), 256, 0, stream>>>(pws, out);
}